// Round 3
// baseline (3549.744 us; speedup 1.0000x reference)
//
#include <hip/hip_runtime.h>
#include <hip/hip_bf16.h>
#include <stdint.h>

#define VOCAB 50257
#define VPAD  50432   /* 197*256 */
#define DIM   640
#define SEQ   256
#define NBATCH 16
#define MROWS 4096    /* NBATCH*SEQ */
#define NT2   20      /* DIM/32 K-tiles for the big GEMM */

using bf16 = __hip_bfloat16;
typedef __attribute__((ext_vector_type(8))) short short8;
typedef __attribute__((ext_vector_type(4))) float f32x4;
struct bf16x4 { bf16 a, b, c, d; };

__device__ __forceinline__ void gld_lds16(const void* g, void* l) {
  __builtin_amdgcn_global_load_lds(
      (const __attribute__((address_space(1))) void*)g,
      (__attribute__((address_space(3))) void*)l, 16, 0, 0);
}

#define BAR() asm volatile("s_barrier" ::: "memory")
#define VMC(n) asm volatile("s_waitcnt vmcnt(" #n ")" ::: "memory")

// ---------------- embed: x = w_embed[idx] + w_pos  -> bf16 ----------------
__global__ void embed_kernel(const int* __restrict__ idx,
                             const float* __restrict__ we,
                             const float* __restrict__ wp,
                             bf16* __restrict__ xb) {
  int row = blockIdx.x;
  int t = row & (SEQ - 1);
  int tok = idx[row];
  const float* src = we + (long)tok * DIM;
  const float* pos = wp + (long)t * DIM;
  for (int d = threadIdx.x * 4; d < DIM; d += blockDim.x * 4) {
    float4 s = *(const float4*)(src + d);
    float4 p = *(const float4*)(pos + d);
    bf16x4 o = { __float2bfloat16(s.x + p.x), __float2bfloat16(s.y + p.y),
                 __float2bfloat16(s.z + p.z), __float2bfloat16(s.w + p.w) };
    *(bf16x4*)(xb + (long)row * DIM + d) = o;
  }
}

// ---------------- f32 -> bf16 convert (x4) with zero tail pad ----------------
__global__ void conv4_kernel(const float* __restrict__ src, bf16* __restrict__ dst,
                             long n_src, long n_dst) {
  long i = ((long)blockIdx.x * blockDim.x + threadIdx.x) * 4;
  long stride = (long)gridDim.x * blockDim.x * 4;
  for (; i < n_dst; i += stride) {
    float4 v = (i < n_src) ? *(const float4*)(src + i) : make_float4(0.f, 0.f, 0.f, 0.f);
    bf16x4 o = { __float2bfloat16(v.x), __float2bfloat16(v.y),
                 __float2bfloat16(v.z), __float2bfloat16(v.w) };
    *(bf16x4*)(dst + i) = o;
  }
}

// ---------------- v (16*256,640) -> vT (16,640,256) ----------------
__global__ void transpose_v(const bf16* __restrict__ v, bf16* __restrict__ vt) {
  long i = (long)blockIdx.x * blockDim.x + threadIdx.x;
  if (i >= (long)NBATCH * DIM * SEQ) return;
  int t = (int)(i & (SEQ - 1));
  long be = i >> 8;
  int e = (int)(be % DIM);
  int b = (int)(be / DIM);
  vt[i] = v[((long)b * SEQ + t) * DIM + e];
}

// ---------------- causal softmax: scores f32 -> P bf16 ----------------
__global__ void softmax_kernel(const float* __restrict__ sc, bf16* __restrict__ p) {
  int wid = threadIdx.x >> 6, lane = threadIdx.x & 63;
  int row = blockIdx.x * 4 + wid;
  int t = row & (SEQ - 1);
  const float* srow = sc + (long)row * SEQ;
  const float rsc = 0.03952847075210474f;  // 1/sqrt(640)
  float v[4];
  float mx = -1e30f;
#pragma unroll
  for (int i = 0; i < 4; ++i) {
    int s = lane + 64 * i;
    v[i] = (s <= t) ? srow[s] * rsc : -1e30f;
    mx = fmaxf(mx, v[i]);
  }
#pragma unroll
  for (int off = 32; off; off >>= 1) mx = fmaxf(mx, __shfl_xor(mx, off, 64));
  float sum = 0.f;
#pragma unroll
  for (int i = 0; i < 4; ++i) {
    int s = lane + 64 * i;
    v[i] = (s <= t) ? __expf(v[i] - mx) : 0.f;
    sum += v[i];
  }
#pragma unroll
  for (int off = 32; off; off >>= 1) sum += __shfl_xor(sum, off, 64);
  float inv = 1.f / sum;
#pragma unroll
  for (int i = 0; i < 4; ++i)
    p[(long)row * SEQ + lane + 64 * i] = __float2bfloat16(v[i] * inv);
}

// ---------------- generic C = A * B^T  (m97-style 128x128 tile) ----------------
template <typename OUT_T, bool BIAS>
__global__ __launch_bounds__(256, 2) void gemm_bt(
    const bf16* __restrict__ Ag, const bf16* __restrict__ Bg,
    OUT_T* __restrict__ Cg, const float* __restrict__ bias,
    int K, int ldc, int Nstore, long sA, long sB, long sC) {
  __shared__ bf16 As[128 * 32];
  __shared__ bf16 Bs[128 * 32];
  const int tid = threadIdx.x;
  const int wv = tid >> 6, lane = tid & 63;
  const int tm = blockIdx.x * 128, tn = blockIdx.y * 128;
  const int bz = blockIdx.z;
  const bf16* A = Ag + (long)bz * sA + (long)tm * K;
  const bf16* B = Bg + (long)bz * sB + (long)tn * K;

  f32x4 acc[4][4] = {};
  const int wr = (wv >> 1) * 64, wc = (wv & 1) * 64;
  const int lr = lane & 15, lk = (lane >> 4) * 8;
  const int srow0 = wv * 32;
  const int g_r = lane >> 2, g_k = (lane & 3) * 8;

  for (int k0 = 0; k0 < K; k0 += 32) {
#pragma unroll
    for (int j = 0; j < 2; ++j) {
      int r = srow0 + j * 16;
      gld_lds16(A + (long)(r + g_r) * K + k0 + g_k, &As[r * 32]);
      gld_lds16(B + (long)(r + g_r) * K + k0 + g_k, &Bs[r * 32]);
    }
    __syncthreads();
    short8 a[4], b[4];
#pragma unroll
    for (int m = 0; m < 4; ++m)
      a[m] = *(const short8*)&As[(wr + m * 16 + lr) * 32 + lk];
#pragma unroll
    for (int n = 0; n < 4; ++n)
      b[n] = *(const short8*)&Bs[(wc + n * 16 + lr) * 32 + lk];
#pragma unroll
    for (int m = 0; m < 4; ++m)
#pragma unroll
      for (int n = 0; n < 4; ++n)
        acc[m][n] = __builtin_amdgcn_mfma_f32_16x16x32_bf16(a[m], b[n], acc[m][n], 0, 0, 0);
    __syncthreads();
  }

  OUT_T* C = Cg + (long)bz * sC;
  const int crow0 = tm + wr + (lane >> 4) * 4;
  const int ccol0 = tn + wc + (lane & 15);
#pragma unroll
  for (int m = 0; m < 4; ++m)
#pragma unroll
    for (int n = 0; n < 4; ++n) {
      int col = ccol0 + n * 16;
      if (col < Nstore) {
        float bv = BIAS ? bias[col] : 0.f;
#pragma unroll
        for (int j = 0; j < 4; ++j) {
          long row = crow0 + m * 16 + j;
          float val = acc[m][n][j] + bv;
          if constexpr (sizeof(OUT_T) == 2)
            C[row * ldc + col] = __float2bfloat16(val);
          else
            C[row * ldc + col] = val;
        }
      }
    }
}

// ============ 256x256 GEMM, BK=32, 64KiB LDS dbuf, 2 blocks/CU ============
// C = A * B^T + bias.  A:(4096,640) bf16, B:(50432,640) bf16 zero-padded.
// 8 waves (2M x 4N), per-wave 128x64 output (acc[8][4]).
// 2 phases/K-tile: p0 {read A(mf0-3)+B(all), stage A(T+1)->other slot},
//                  p1 {read A(mf4-7), stage B(T+2)->this slot, vmcnt(2)}.
// B staged 2 tiles ahead, A 1 tile; 2 loads cross each tile boundary.
// LDS 16B-block swizzle sigma(beta)=beta^((beta>>3)&3) applied both-sides
// (pre-swizzled global source for gld_lds + swizzled ds_read address).
__global__ __launch_bounds__(512, 4) void gemm256v2(
    const bf16* __restrict__ Ag, const bf16* __restrict__ Bg,
    float* __restrict__ Cg, const float* __restrict__ bias) {
  __shared__ __align__(16) char lds[65536];   // [2 slots][A 16KB | B 16KB]
  const int tid = threadIdx.x;
  const int lane = tid & 63, wv = tid >> 6;
  const int wm = wv >> 2, wn = wv & 3;
  const int lr = lane & 15, h16 = lane >> 4;

  // XCD-aware bijective swizzle (3152 = 8*394), tm-fastest for B-panel L2 reuse
  int bid = blockIdx.x;
  int swz = (bid & 7) * 394 + (bid >> 3);
  const int tm = swz & 15, tn = swz >> 4;

  const bf16* Abase = Ag + (long)tm * 256 * DIM;
  const bf16* Bbase = Bg + (long)tn * 256 * DIM;

  // staging: physical 16B-block delta = j*512 + wv*64 + lane; logical beta = sigma(delta)
  int srcE[2], dstO[2];
#pragma unroll
  for (int j = 0; j < 2; ++j) {
    int d = j * 512 + wv * 64 + lane;
    int b = d ^ ((d >> 3) & 3);
    srcE[j] = (b >> 2) * DIM + (b & 3) * 8;   // row*(ld=DIM) + 8-elem slot
    dstO[j] = (j * 512 + wv * 64) * 16;       // wave-uniform byte base
  }
  auto STAGE = [&](int slotByte, const bf16* src, int kOff) {
#pragma unroll
    for (int j = 0; j < 2; ++j)
      gld_lds16(src + srcE[j] + kOff, lds + slotByte + dstO[j]);
  };

  // swizzled ds_read byte offsets (constant per lane)
  int aoff[8], boff[4];
#pragma unroll
  for (int mf = 0; mf < 8; ++mf) {
    int r = wm * 128 + mf * 16 + lr;
    int L = r * 64 + h16 * 16;
    aoff[mf] = L ^ (((L >> 7) & 3) << 4);
  }
#pragma unroll
  for (int nf = 0; nf < 4; ++nf) {
    int r = wn * 64 + nf * 16 + lr;
    int L = r * 64 + h16 * 16;
    boff[nf] = 16384 + (L ^ (((L >> 7) & 3) << 4));
  }

  f32x4 acc[8][4] = {};
  short8 a[4], b[4];

#define MFMA16(ROFF)                                                          \
  __builtin_amdgcn_s_setprio(1);                                              \
  { _Pragma("unroll") for (int m = 0; m < 4; ++m)                             \
    _Pragma("unroll") for (int n = 0; n < 4; ++n)                             \
      acc[(ROFF) + m][n] = __builtin_amdgcn_mfma_f32_16x16x32_bf16(           \
          a[m], b[n], acc[(ROFF) + m][n], 0, 0, 0); }                         \
  __builtin_amdgcn_s_setprio(0);

  // prologue: A(0), B(0) -> slot0 ; B(1) -> slot1. vmcnt(2) keeps B(1) flying.
  STAGE(0, Abase, 0);
  STAGE(16384, Bbase, 0);
  STAGE(32768 + 16384, Bbase, 32);
  VMC(2);
  BAR();

#pragma unroll
  for (int T = 0; T < NT2; ++T) {
    const int slot = (T & 1) * 32768;
    const int nslot = ((T + 1) & 1) * 32768;
    // ---- phase 0: read A(mf0-3) + B(all); stage A(T+1) into other slot
#pragma unroll
    for (int m = 0; m < 4; ++m) a[m] = *(const short8*)(lds + slot + aoff[m]);
#pragma unroll
    for (int n = 0; n < 4; ++n) b[n] = *(const short8*)(lds + slot + boff[n]);
    if (T + 1 < NT2) STAGE(nslot, Abase, (T + 1) * 32);
    BAR();
    MFMA16(0);
    BAR();
    // ---- phase 1: read A(mf4-7); stage B(T+2) into this slot (B reads done @p0)
#pragma unroll
    for (int m = 0; m < 4; ++m) a[m] = *(const short8*)(lds + slot + aoff[m + 4]);
    if (T + 2 < NT2) {
      STAGE(slot + 16384, Bbase, (T + 2) * 32);
      VMC(2);
    } else if (T + 1 < NT2) {
      VMC(0);
    }
    BAR();
    MFMA16(4);
    BAR();
  }
#undef MFMA16

  // ---- epilogue: C write + bias, masked to col < VOCAB
  const int rowB = tm * 256 + wm * 128 + h16 * 4;
  const int colB = tn * 256 + wn * 64 + lr;
#pragma unroll
  for (int mf = 0; mf < 8; ++mf)
#pragma unroll
    for (int nf = 0; nf < 4; ++nf) {
      int col = colB + nf * 16;
      if (col < VOCAB) {
        float bv = bias[col];
#pragma unroll
        for (int jj = 0; jj < 4; ++jj)
          Cg[(long)(rowB + mf * 16 + jj) * VOCAB + col] = acc[mf][nf][jj] + bv;
      }
    }
}

extern "C" void kernel_launch(void* const* d_in, const int* in_sizes, int n_in,
                              void* d_out, int out_size, void* d_ws, size_t ws_size,
                              hipStream_t stream) {
  const int*   idx     = (const int*)d_in[0];
  const float* w_embed = (const float*)d_in[1];
  const float* w_pos   = (const float*)d_in[2];
  const float* wq      = (const float*)d_in[3];
  const float* wk      = (const float*)d_in[4];
  const float* wv      = (const float*)d_in[5];
  const float* w_out   = (const float*)d_in[6];
  const float* b_out   = (const float*)d_in[7];
  float* out = (float*)d_out;

  size_t off = 0;
  auto alloc = [&](size_t bytes) {
    void* p = (char*)d_ws + off;
    off += (bytes + 255) & ~(size_t)255;
    return p;
  };
  bf16* x_bf    = (bf16*)alloc((size_t)MROWS * DIM * 2);
  bf16* wqkv_bf = (bf16*)alloc((size_t)3 * DIM * DIM * 2);
  bf16* wout_bf = (bf16*)alloc((size_t)VPAD * DIM * 2);
  bf16* qkv     = (bf16*)alloc((size_t)3 * MROWS * DIM * 2);
  bf16* vT      = (bf16*)alloc((size_t)NBATCH * DIM * SEQ * 2);
  float* scores = (float*)alloc((size_t)NBATCH * SEQ * SEQ * 4);
  bf16* P       = (bf16*)alloc((size_t)NBATCH * SEQ * SEQ * 2);
  bf16* attn    = (bf16*)alloc((size_t)MROWS * DIM * 2);

  const long QKV_S = (long)MROWS * DIM;
  const long W_S   = (long)DIM * DIM;

  // 1. embed
  embed_kernel<<<MROWS, 256, 0, stream>>>(idx, w_embed, w_pos, x_bf);

  // 2. weight converts (bf16; w_out zero-padded to VPAD rows)
  conv4_kernel<<<256, 256, 0, stream>>>(wq, wqkv_bf,           W_S, W_S);
  conv4_kernel<<<256, 256, 0, stream>>>(wk, wqkv_bf + W_S,     W_S, W_S);
  conv4_kernel<<<256, 256, 0, stream>>>(wv, wqkv_bf + 2 * W_S, W_S, W_S);
  conv4_kernel<<<2048, 256, 0, stream>>>(w_out, wout_bf, (long)VOCAB * DIM, (long)VPAD * DIM);

  // 3. q,k,v = x @ {wq,wk,wv}^T
  gemm_bt<bf16, false><<<dim3(MROWS / 128, DIM / 128, 3), 256, 0, stream>>>(
      x_bf, wqkv_bf, qkv, nullptr, DIM, DIM, DIM, 0, W_S, QKV_S);

  // 4. vT per batch
  {
    long n = (long)NBATCH * DIM * SEQ;
    transpose_v<<<(int)((n + 255) / 256), 256, 0, stream>>>(qkv + 2 * QKV_S, vT);
  }

  // 5. scores[b] = q[b] @ k[b]^T
  gemm_bt<float, false><<<dim3(SEQ / 128, SEQ / 128, NBATCH), 256, 0, stream>>>(
      qkv, qkv + QKV_S, scores, nullptr, DIM, SEQ, SEQ,
      (long)SEQ * DIM, (long)SEQ * DIM, (long)SEQ * SEQ);

  // 6. causal softmax -> P bf16
  softmax_kernel<<<MROWS / 4, 256, 0, stream>>>(scores, P);

  // 7. attn[b] = P[b] @ vT[b]^T
  gemm_bt<bf16, false><<<dim3(SEQ / 128, DIM / 128, NBATCH), 256, 0, stream>>>(
      P, vT, attn, nullptr, SEQ, DIM, DIM,
      (long)SEQ * SEQ, (long)DIM * SEQ, (long)SEQ * DIM);

  // 8. logits = attn @ w_out^T + b_out  (256x256 BK=32, 2 blocks/CU)
  gemm256v2<<<16 * 197, 512, 0, stream>>>(attn, wout_bf, out, b_out);
}

// Round 4
// 742.014 us; speedup vs baseline: 4.7839x; 4.7839x over previous
//
#include <hip/hip_runtime.h>
#include <hip/hip_bf16.h>
#include <stdint.h>

#define VOCAB 50257
#define VPAD  50432   /* 394*128 */
#define DIM   640
#define SEQ   256
#define NBATCH 16
#define MROWS 4096    /* NBATCH*SEQ */

using bf16 = __hip_bfloat16;
typedef __attribute__((ext_vector_type(8))) short short8;
typedef __attribute__((ext_vector_type(4))) float f32x4;
struct bf16x4 { bf16 a, b, c, d; };

__device__ __forceinline__ void gld_lds16(const void* g, void* l) {
  __builtin_amdgcn_global_load_lds(
      (const __attribute__((address_space(1))) void*)g,
      (__attribute__((address_space(3))) void*)l, 16, 0, 0);
}

#define BAR() asm volatile("s_barrier" ::: "memory")
#define VMC(n) asm volatile("s_waitcnt vmcnt(" #n ")" ::: "memory")

// ---------------- embed: x = w_embed[idx] + w_pos  -> bf16 ----------------
__global__ void embed_kernel(const int* __restrict__ idx,
                             const float* __restrict__ we,
                             const float* __restrict__ wp,
                             bf16* __restrict__ xb) {
  int row = blockIdx.x;
  int t = row & (SEQ - 1);
  int tok = idx[row];
  const float* src = we + (long)tok * DIM;
  const float* pos = wp + (long)t * DIM;
  for (int d = threadIdx.x * 4; d < DIM; d += blockDim.x * 4) {
    float4 s = *(const float4*)(src + d);
    float4 p = *(const float4*)(pos + d);
    bf16x4 o = { __float2bfloat16(s.x + p.x), __float2bfloat16(s.y + p.y),
                 __float2bfloat16(s.z + p.z), __float2bfloat16(s.w + p.w) };
    *(bf16x4*)(xb + (long)row * DIM + d) = o;
  }
}

// ---------------- f32 -> bf16 convert (x4) with zero tail pad ----------------
__global__ void conv4_kernel(const float* __restrict__ src, bf16* __restrict__ dst,
                             long n_src, long n_dst) {
  long i = ((long)blockIdx.x * blockDim.x + threadIdx.x) * 4;
  long stride = (long)gridDim.x * blockDim.x * 4;
  for (; i < n_dst; i += stride) {
    float4 v = (i < n_src) ? *(const float4*)(src + i) : make_float4(0.f, 0.f, 0.f, 0.f);
    bf16x4 o = { __float2bfloat16(v.x), __float2bfloat16(v.y),
                 __float2bfloat16(v.z), __float2bfloat16(v.w) };
    *(bf16x4*)(dst + i) = o;
  }
}

// ---------------- v (16*256,640) -> vT (16,640,256) ----------------
__global__ void transpose_v(const bf16* __restrict__ v, bf16* __restrict__ vt) {
  long i = (long)blockIdx.x * blockDim.x + threadIdx.x;
  if (i >= (long)NBATCH * DIM * SEQ) return;
  int t = (int)(i & (SEQ - 1));
  long be = i >> 8;
  int e = (int)(be % DIM);
  int b = (int)(be / DIM);
  vt[i] = v[((long)b * SEQ + t) * DIM + e];
}

// ---------------- causal softmax: scores f32 -> P bf16 ----------------
__global__ void softmax_kernel(const float* __restrict__ sc, bf16* __restrict__ p) {
  int wid = threadIdx.x >> 6, lane = threadIdx.x & 63;
  int row = blockIdx.x * 4 + wid;
  int t = row & (SEQ - 1);
  const float* srow = sc + (long)row * SEQ;
  const float rsc = 0.03952847075210474f;  // 1/sqrt(640)
  float v[4];
  float mx = -1e30f;
#pragma unroll
  for (int i = 0; i < 4; ++i) {
    int s = lane + 64 * i;
    v[i] = (s <= t) ? srow[s] * rsc : -1e30f;
    mx = fmaxf(mx, v[i]);
  }
#pragma unroll
  for (int off = 32; off; off >>= 1) mx = fmaxf(mx, __shfl_xor(mx, off, 64));
  float sum = 0.f;
#pragma unroll
  for (int i = 0; i < 4; ++i) {
    int s = lane + 64 * i;
    v[i] = (s <= t) ? __expf(v[i] - mx) : 0.f;
    sum += v[i];
  }
#pragma unroll
  for (int off = 32; off; off >>= 1) sum += __shfl_xor(sum, off, 64);
  float inv = 1.f / sum;
#pragma unroll
  for (int i = 0; i < 4; ++i)
    p[(long)row * SEQ + lane + 64 * i] = __float2bfloat16(v[i] * inv);
}

// ========= pipelined 128x128 GEMM: C = A * B^T (+bias) =========
// A: (Mtiles*128, K) bf16, B: (Ntiles*128, K) bf16, row-major.
// 4 waves (2Mx2N), per-wave 64x64 (acc[4][4]). BK=32.
// 3-slot LDS ring (48 KiB -> 3 blocks/CU), staged 2 tiles ahead,
// counted vmcnt(4) (never 0 mid-loop), raw s_barrier, setprio on MFMA.
// 16B-block LDS swizzle sigma(beta)=beta^((beta>>3)&3), both-sides
// (pre-swizzled gld_lds source + swizzled ds_read) -> 2-way conflicts (free).
// SWZ: chunked XCD blockIdx swizzle (grid must be divisible by 8).
template <int NT, typename OUT_T, bool BIAS, bool SWZ>
__global__ __launch_bounds__(256, 3) void gemm_pipe(
    const bf16* __restrict__ Ag, const bf16* __restrict__ Bg,
    OUT_T* __restrict__ Cg, const float* __restrict__ bias,
    int K, int ldc, int Nstore, long sA, long sB, long sC,
    int tmW, int chunk) {
  __shared__ __align__(16) char lds[49152];   // 3 slots x [A 8KB | B 8KB]
  const int tid = threadIdx.x;
  const int lane = tid & 63, wv = tid >> 6;
  const int lr = lane & 15, h16 = lane >> 4;

  int tm, tn, bz;
  if constexpr (SWZ) {
    int bid = blockIdx.x;
    int s = (bid & 7) * chunk + (bid >> 3);  // XCD-chunked, bijective (grid%8==0)
    tm = s % tmW; tn = s / tmW; bz = 0;
  } else {
    tm = blockIdx.x; tn = blockIdx.y; bz = blockIdx.z;
  }

  const bf16* A = Ag + (long)bz * sA + (long)tm * 128 * K;
  const bf16* B = Bg + (long)bz * sB + (long)tn * 128 * K;

  // staging: physical 16B-block delta -> logical beta = sigma(delta)
  int srcE[2], dstW[2];
#pragma unroll
  for (int j = 0; j < 2; ++j) {
    int d = j * 256 + tid;
    int b = d ^ ((d >> 3) & 3);
    srcE[j] = (b >> 2) * K + (b & 3) * 8;   // row*K + 8-elem col slot
    dstW[j] = (j * 256 + wv * 64) * 16;     // wave-uniform byte base (+lane*16 by HW)
  }
  auto STAGE = [&](int slot, int kOff) {
#pragma unroll
    for (int j = 0; j < 2; ++j) {
      gld_lds16(A + srcE[j] + kOff, lds + slot + dstW[j]);
      gld_lds16(B + srcE[j] + kOff, lds + slot + 8192 + dstW[j]);
    }
  };

  // swizzled ds_read byte offsets (constant per lane)
  const int wr = (wv >> 1) * 64, wc = (wv & 1) * 64;
  int aoff[4], boff[4];
#pragma unroll
  for (int m = 0; m < 4; ++m) {
    int La = (wr + m * 16 + lr) * 64 + h16 * 16;
    aoff[m] = La ^ (((La >> 7) & 3) << 4);
    int Lb = (wc + m * 16 + lr) * 64 + h16 * 16;
    boff[m] = 8192 + (Lb ^ (((Lb >> 7) & 3) << 4));
  }

  f32x4 acc[4][4] = {};
  short8 a[4], b[4];

  // prologue: tile0 -> slot0 (landed), tile1 -> slot1 (flying)
  STAGE(0, 0);
  if (NT > 1) STAGE(16384, 32);
  VMC(4);
  BAR();

#pragma unroll
  for (int t = 0; t < NT; ++t) {
    const int cur = (t % 3) * 16384;
    if (t + 2 < NT) STAGE(((t + 2) % 3) * 16384, (t + 2) * 32);
#pragma unroll
    for (int m = 0; m < 4; ++m) a[m] = *(const short8*)(lds + cur + aoff[m]);
#pragma unroll
    for (int n = 0; n < 4; ++n) b[n] = *(const short8*)(lds + cur + boff[n]);
    __builtin_amdgcn_s_setprio(1);
#pragma unroll
    for (int m = 0; m < 4; ++m)
#pragma unroll
      for (int n = 0; n < 4; ++n)
        acc[m][n] = __builtin_amdgcn_mfma_f32_16x16x32_bf16(a[m], b[n], acc[m][n], 0, 0, 0);
    __builtin_amdgcn_s_setprio(0);
    if (t + 2 < NT) { VMC(4); }
    else if (t + 1 < NT) { VMC(0); }
    BAR();
  }

  // epilogue: C write (+bias), masked to col < Nstore
  OUT_T* C = Cg + (long)bz * sC;
  const int crow0 = tm * 128 + wr + h16 * 4;
  const int ccol0 = tn * 128 + wc + lr;
#pragma unroll
  for (int m = 0; m < 4; ++m)
#pragma unroll
    for (int n = 0; n < 4; ++n) {
      int col = ccol0 + n * 16;
      if (col < Nstore) {
        float bv = BIAS ? bias[col] : 0.f;
#pragma unroll
        for (int j = 0; j < 4; ++j) {
          long row = crow0 + m * 16 + j;
          float val = acc[m][n][j] + bv;
          if constexpr (sizeof(OUT_T) == 2)
            C[row * ldc + col] = __float2bfloat16(val);
          else
            C[row * ldc + col] = val;
        }
      }
    }
}

extern "C" void kernel_launch(void* const* d_in, const int* in_sizes, int n_in,
                              void* d_out, int out_size, void* d_ws, size_t ws_size,
                              hipStream_t stream) {
  const int*   idx     = (const int*)d_in[0];
  const float* w_embed = (const float*)d_in[1];
  const float* w_pos   = (const float*)d_in[2];
  const float* wq      = (const float*)d_in[3];
  const float* wk      = (const float*)d_in[4];
  const float* wv      = (const float*)d_in[5];
  const float* w_out   = (const float*)d_in[6];
  const float* b_out   = (const float*)d_in[7];
  float* out = (float*)d_out;

  size_t off = 0;
  auto alloc = [&](size_t bytes) {
    void* p = (char*)d_ws + off;
    off += (bytes + 255) & ~(size_t)255;
    return p;
  };
  bf16* x_bf    = (bf16*)alloc((size_t)MROWS * DIM * 2);
  bf16* wqkv_bf = (bf16*)alloc((size_t)3 * DIM * DIM * 2);
  bf16* wout_bf = (bf16*)alloc((size_t)VPAD * DIM * 2);
  bf16* qkv     = (bf16*)alloc((size_t)3 * MROWS * DIM * 2);
  bf16* vT      = (bf16*)alloc((size_t)NBATCH * DIM * SEQ * 2);
  float* scores = (float*)alloc((size_t)NBATCH * SEQ * SEQ * 4);
  bf16* P       = (bf16*)alloc((size_t)NBATCH * SEQ * SEQ * 2);
  bf16* attn    = (bf16*)alloc((size_t)MROWS * DIM * 2);

  const long QKV_S = (long)MROWS * DIM;
  const long W_S   = (long)DIM * DIM;

  // 1. embed
  embed_kernel<<<MROWS, 256, 0, stream>>>(idx, w_embed, w_pos, x_bf);

  // 2. weight converts (bf16; w_out zero-padded to VPAD rows)
  conv4_kernel<<<256, 256, 0, stream>>>(wq, wqkv_bf,           W_S, W_S);
  conv4_kernel<<<256, 256, 0, stream>>>(wk, wqkv_bf + W_S,     W_S, W_S);
  conv4_kernel<<<256, 256, 0, stream>>>(wv, wqkv_bf + 2 * W_S, W_S, W_S);
  conv4_kernel<<<2048, 256, 0, stream>>>(w_out, wout_bf, (long)VOCAB * DIM, (long)VPAD * DIM);

  // 3. q,k,v = x @ {wq,wk,wv}^T   (K=640 -> NT=20)
  gemm_pipe<20, bf16, false, false><<<dim3(MROWS / 128, DIM / 128, 3), 256, 0, stream>>>(
      x_bf, wqkv_bf, qkv, nullptr, DIM, DIM, DIM, 0, W_S, QKV_S, 0, 0);

  // 4. vT per batch
  {
    long n = (long)NBATCH * DIM * SEQ;
    transpose_v<<<(int)((n + 255) / 256), 256, 0, stream>>>(qkv + 2 * QKV_S, vT);
  }

  // 5. scores[b] = q[b] @ k[b]^T  (K=640 -> NT=20)
  gemm_pipe<20, float, false, false><<<dim3(SEQ / 128, SEQ / 128, NBATCH), 256, 0, stream>>>(
      qkv, qkv + QKV_S, scores, nullptr, DIM, SEQ, SEQ,
      (long)SEQ * DIM, (long)SEQ * DIM, (long)SEQ * SEQ, 0, 0);

  // 6. causal softmax -> P bf16
  softmax_kernel<<<MROWS / 4, 256, 0, stream>>>(scores, P);

  // 7. attn[b] = P[b] @ vT[b]^T  (K=256 -> NT=8)
  gemm_pipe<8, bf16, false, false><<<dim3(SEQ / 128, DIM / 128, NBATCH), 256, 0, stream>>>(
      P, vT, attn, nullptr, SEQ, DIM, DIM,
      (long)SEQ * SEQ, (long)DIM * SEQ, (long)SEQ * DIM, 0, 0);

  // 8. logits = attn @ w_out^T + b_out  (12608 blocks = 8*1576, XCD-chunked)
  gemm_pipe<20, float, true, true><<<12608, 256, 0, stream>>>(
      attn, wout_bf, out, b_out, DIM, VOCAB, VOCAB, 0, 0, 0, 32, 1576);
}

// Round 5
// 607.549 us; speedup vs baseline: 5.8427x; 1.2213x over previous
//
#include <hip/hip_runtime.h>
#include <hip/hip_bf16.h>
#include <stdint.h>

#define VOCAB 50257
#define VPAD  50432   /* 394*128 */
#define DIM   640
#define SEQ   256
#define NBATCH 16
#define MROWS 4096    /* NBATCH*SEQ */

using bf16 = __hip_bfloat16;
typedef __attribute__((ext_vector_type(8))) short short8;
typedef __attribute__((ext_vector_type(4))) float f32x4;
struct bf16x4 { bf16 a, b, c, d; };

__device__ __forceinline__ void gld_lds16(const void* g, void* l) {
  __builtin_amdgcn_global_load_lds(
      (const __attribute__((address_space(1))) void*)g,
      (__attribute__((address_space(3))) void*)l, 16, 0, 0);
}

#define BAR() asm volatile("s_barrier" ::: "memory")
#define VMC0() asm volatile("s_waitcnt vmcnt(0)" ::: "memory")

// ---------------- embed: x = w_embed[idx] + w_pos  -> bf16 ----------------
__global__ void embed_kernel(const int* __restrict__ idx,
                             const float* __restrict__ we,
                             const float* __restrict__ wp,
                             bf16* __restrict__ xb) {
  int row = blockIdx.x;
  int t = row & (SEQ - 1);
  int tok = idx[row];
  const float* src = we + (long)tok * DIM;
  const float* pos = wp + (long)t * DIM;
  for (int d = threadIdx.x * 4; d < DIM; d += blockDim.x * 4) {
    float4 s = *(const float4*)(src + d);
    float4 p = *(const float4*)(pos + d);
    bf16x4 o = { __float2bfloat16(s.x + p.x), __float2bfloat16(s.y + p.y),
                 __float2bfloat16(s.z + p.z), __float2bfloat16(s.w + p.w) };
    *(bf16x4*)(xb + (long)row * DIM + d) = o;
  }
}

// ---------------- f32 -> bf16 convert (x4) with zero tail pad ----------------
__global__ void conv4_kernel(const float* __restrict__ src, bf16* __restrict__ dst,
                             long n_src, long n_dst) {
  long i = ((long)blockIdx.x * blockDim.x + threadIdx.x) * 4;
  long stride = (long)gridDim.x * blockDim.x * 4;
  for (; i < n_dst; i += stride) {
    float4 v = (i < n_src) ? *(const float4*)(src + i) : make_float4(0.f, 0.f, 0.f, 0.f);
    bf16x4 o = { __float2bfloat16(v.x), __float2bfloat16(v.y),
                 __float2bfloat16(v.z), __float2bfloat16(v.w) };
    *(bf16x4*)(dst + i) = o;
  }
}

// ---------------- v (16*256,640) -> vT (16,640,256) ----------------
__global__ void transpose_v(const bf16* __restrict__ v, bf16* __restrict__ vt) {
  long i = (long)blockIdx.x * blockDim.x + threadIdx.x;
  if (i >= (long)NBATCH * DIM * SEQ) return;
  int t = (int)(i & (SEQ - 1));
  long be = i >> 8;
  int e = (int)(be % DIM);
  int b = (int)(be / DIM);
  vt[i] = v[((long)b * SEQ + t) * DIM + e];
}

// ---------------- causal softmax: scores f32 -> P bf16 ----------------
__global__ void softmax_kernel(const float* __restrict__ sc, bf16* __restrict__ p) {
  int wid = threadIdx.x >> 6, lane = threadIdx.x & 63;
  int row = blockIdx.x * 4 + wid;
  int t = row & (SEQ - 1);
  const float* srow = sc + (long)row * SEQ;
  const float rsc = 0.03952847075210474f;  // 1/sqrt(640)
  float v[4];
  float mx = -1e30f;
#pragma unroll
  for (int i = 0; i < 4; ++i) {
    int s = lane + 64 * i;
    v[i] = (s <= t) ? srow[s] * rsc : -1e30f;
    mx = fmaxf(mx, v[i]);
  }
#pragma unroll
  for (int off = 32; off; off >>= 1) mx = fmaxf(mx, __shfl_xor(mx, off, 64));
  float sum = 0.f;
#pragma unroll
  for (int i = 0; i < 4; ++i) {
    int s = lane + 64 * i;
    v[i] = (s <= t) ? __expf(v[i] - mx) : 0.f;
    sum += v[i];
  }
#pragma unroll
  for (int off = 32; off; off >>= 1) sum += __shfl_xor(sum, off, 64);
  float inv = 1.f / sum;
#pragma unroll
  for (int i = 0; i < 4; ++i)
    p[(long)row * SEQ + lane + 64 * i] = __float2bfloat16(v[i] * inv);
}

// ========= 128x128 GEMM, T3-minimum 2-phase pipeline: C = A * B^T (+bias) =========
// A: (Mtiles*128, K) bf16, B: (Ntiles*128, K) bf16, row-major.
// 4 waves (2Mx2N), per-wave 64x64 (acc[4][4]). BK=32.
// 2-slot LDS ring (32 KiB -> reg-limited ~4 blocks/CU = 16 waves),
// per tile: {STAGE next -> other slot; ds_read cur; MFMA; vmcnt(0); s_barrier}.
// Loads get ds_read+MFMA time of latency cover (r1 baseline had zero).
// 16B-block LDS swizzle sigma(beta)=beta^((beta>>3)&3) both-sides (HW-verified r4,
// SQ_LDS_BANK_CONFLICT=0). Natural grid order (tm=blockIdx.x fastest) -- NO XCD
// swizzle: r4 showed chunked swizzle thrashes L3 here (FETCH 267MB->1GB).
template <int NT, typename OUT_T, bool BIAS>
__global__ __launch_bounds__(256, 4) void gemm_pipe(
    const bf16* __restrict__ Ag, const bf16* __restrict__ Bg,
    OUT_T* __restrict__ Cg, const float* __restrict__ bias,
    int K, int ldc, int Nstore, long sA, long sB, long sC) {
  __shared__ __align__(16) char lds[32768];   // 2 slots x [A 8KB | B 8KB]
  const int tid = threadIdx.x;
  const int lane = tid & 63, wv = tid >> 6;
  const int lr = lane & 15, h16 = lane >> 4;

  const int tm = blockIdx.x, tn = blockIdx.y, bz = blockIdx.z;
  const bf16* A = Ag + (long)bz * sA + (long)tm * 128 * K;
  const bf16* B = Bg + (long)bz * sB + (long)tn * 128 * K;

  // staging: physical 16B-block delta -> logical beta = sigma(delta)
  int srcE[2], dstW[2];
#pragma unroll
  for (int j = 0; j < 2; ++j) {
    int d = j * 256 + tid;
    int b = d ^ ((d >> 3) & 3);
    srcE[j] = (b >> 2) * K + (b & 3) * 8;   // row*K + 8-elem col slot
    dstW[j] = (j * 256 + wv * 64) * 16;     // wave-uniform byte base (+lane*16 by HW)
  }
  const bf16* aS0 = A + srcE[0];
  const bf16* aS1 = A + srcE[1];
  const bf16* bS0 = B + srcE[0];
  const bf16* bS1 = B + srcE[1];
  auto STAGE = [&](int slot, int t) {
    int kOff = t * 32;
    gld_lds16(aS0 + kOff, lds + slot + dstW[0]);
    gld_lds16(aS1 + kOff, lds + slot + dstW[1]);
    gld_lds16(bS0 + kOff, lds + slot + 8192 + dstW[0]);
    gld_lds16(bS1 + kOff, lds + slot + 8192 + dstW[1]);
  };

  // swizzled ds_read byte offsets (constant per lane)
  const int wr = (wv >> 1) * 64, wc = (wv & 1) * 64;
  int aoff[4], boff[4];
#pragma unroll
  for (int m = 0; m < 4; ++m) {
    int La = (wr + m * 16 + lr) * 64 + h16 * 16;
    aoff[m] = La ^ (((La >> 7) & 3) << 4);
    int Lb = (wc + m * 16 + lr) * 64 + h16 * 16;
    boff[m] = 8192 + (Lb ^ (((Lb >> 7) & 3) << 4));
  }

  f32x4 acc[4][4] = {};
  short8 a[4], b[4];

  // prologue: tile0 -> slot0, landed before loop
  STAGE(0, 0);
  VMC0();
  BAR();

#pragma unroll 2
  for (int t = 0; t < NT; ++t) {
    const int cur = (t & 1) * 16384;
    if (t + 1 < NT) STAGE(16384 - cur, t + 1);   // other slot; its reads sealed @t-1
#pragma unroll
    for (int m = 0; m < 4; ++m) a[m] = *(const short8*)(lds + cur + aoff[m]);
#pragma unroll
    for (int n = 0; n < 4; ++n) b[n] = *(const short8*)(lds + cur + boff[n]);
    __builtin_amdgcn_s_setprio(1);
#pragma unroll
    for (int m = 0; m < 4; ++m)
#pragma unroll
      for (int n = 0; n < 4; ++n)
        acc[m][n] = __builtin_amdgcn_mfma_f32_16x16x32_bf16(a[m], b[n], acc[m][n], 0, 0, 0);
    __builtin_amdgcn_s_setprio(0);
    if (t + 1 < NT) VMC0();   // next tile landed (covered by ds_read+MFMA time)
    BAR();
  }

  // epilogue: C write (+bias), masked to col < Nstore
  OUT_T* C = Cg + (long)bz * sC;
  const int crow0 = tm * 128 + wr + h16 * 4;
  const int ccol0 = tn * 128 + wc + lr;
#pragma unroll
  for (int m = 0; m < 4; ++m)
#pragma unroll
    for (int n = 0; n < 4; ++n) {
      int col = ccol0 + n * 16;
      if (col < Nstore) {
        float bv = BIAS ? bias[col] : 0.f;
#pragma unroll
        for (int j = 0; j < 4; ++j) {
          long row = crow0 + m * 16 + j;
          float val = acc[m][n][j] + bv;
          if constexpr (sizeof(OUT_T) == 2)
            C[row * ldc + col] = __float2bfloat16(val);
          else
            C[row * ldc + col] = val;
        }
      }
    }
}

extern "C" void kernel_launch(void* const* d_in, const int* in_sizes, int n_in,
                              void* d_out, int out_size, void* d_ws, size_t ws_size,
                              hipStream_t stream) {
  const int*   idx     = (const int*)d_in[0];
  const float* w_embed = (const float*)d_in[1];
  const float* w_pos   = (const float*)d_in[2];
  const float* wq      = (const float*)d_in[3];
  const float* wk      = (const float*)d_in[4];
  const float* wv      = (const float*)d_in[5];
  const float* w_out   = (const float*)d_in[6];
  const float* b_out   = (const float*)d_in[7];
  float* out = (float*)d_out;

  size_t off = 0;
  auto alloc = [&](size_t bytes) {
    void* p = (char*)d_ws + off;
    off += (bytes + 255) & ~(size_t)255;
    return p;
  };
  bf16* x_bf    = (bf16*)alloc((size_t)MROWS * DIM * 2);
  bf16* wqkv_bf = (bf16*)alloc((size_t)3 * DIM * DIM * 2);
  bf16* wout_bf = (bf16*)alloc((size_t)VPAD * DIM * 2);
  bf16* qkv     = (bf16*)alloc((size_t)3 * MROWS * DIM * 2);
  bf16* vT      = (bf16*)alloc((size_t)NBATCH * DIM * SEQ * 2);
  float* scores = (float*)alloc((size_t)NBATCH * SEQ * SEQ * 4);
  bf16* P       = (bf16*)alloc((size_t)NBATCH * SEQ * SEQ * 2);
  bf16* attn    = (bf16*)alloc((size_t)MROWS * DIM * 2);

  const long QKV_S = (long)MROWS * DIM;
  const long W_S   = (long)DIM * DIM;

  // 1. embed
  embed_kernel<<<MROWS, 256, 0, stream>>>(idx, w_embed, w_pos, x_bf);

  // 2. weight converts (bf16; w_out zero-padded to VPAD rows)
  conv4_kernel<<<256, 256, 0, stream>>>(wq, wqkv_bf,           W_S, W_S);
  conv4_kernel<<<256, 256, 0, stream>>>(wk, wqkv_bf + W_S,     W_S, W_S);
  conv4_kernel<<<256, 256, 0, stream>>>(wv, wqkv_bf + 2 * W_S, W_S, W_S);
  conv4_kernel<<<2048, 256, 0, stream>>>(w_out, wout_bf, (long)VOCAB * DIM, (long)VPAD * DIM);

  // 3. q,k,v = x @ {wq,wk,wv}^T   (K=640 -> NT=20)
  gemm_pipe<20, bf16, false><<<dim3(MROWS / 128, DIM / 128, 3), 256, 0, stream>>>(
      x_bf, wqkv_bf, qkv, nullptr, DIM, DIM, DIM, 0, W_S, QKV_S);

  // 4. vT per batch
  {
    long n = (long)NBATCH * DIM * SEQ;
    transpose_v<<<(int)((n + 255) / 256), 256, 0, stream>>>(qkv + 2 * QKV_S, vT);
  }

  // 5. scores[b] = q[b] @ k[b]^T  (K=640 -> NT=20)
  gemm_pipe<20, float, false><<<dim3(SEQ / 128, SEQ / 128, NBATCH), 256, 0, stream>>>(
      qkv, qkv + QKV_S, scores, nullptr, DIM, SEQ, SEQ,
      (long)SEQ * DIM, (long)SEQ * DIM, (long)SEQ * SEQ);

  // 6. causal softmax -> P bf16
  softmax_kernel<<<MROWS / 4, 256, 0, stream>>>(scores, P);

  // 7. attn[b] = P[b] @ vT[b]^T  (K=256 -> NT=8)
  gemm_pipe<8, bf16, false><<<dim3(SEQ / 128, DIM / 128, NBATCH), 256, 0, stream>>>(
      P, vT, attn, nullptr, SEQ, DIM, DIM,
      (long)SEQ * SEQ, (long)DIM * SEQ, (long)SEQ * DIM);

  // 8. logits = attn @ w_out^T + b_out  (natural order: tm fastest)
  gemm_pipe<20, float, true><<<dim3(MROWS / 128, VPAD / 128, 1), 256, 0, stream>>>(
      attn, wout_bf, out, b_out, DIM, VOCAB, VOCAB, 0, 0, 0);
}